// Round 6
// baseline (753.118 us; speedup 1.0000x reference)
//
#include <hip/hip_runtime.h>
#include <math.h>

// Attention_80779744903968 — round 9 (= round 8 resubmitted; r8 bench died
// of a container-infra failure before executing the kernel; audit found no
// hang mechanism: uniform barriers, monotone vmcnt plan, race-free 3-slot
// rotation, bijective swizzles).
//
//   Synthesis of r4 (counted-vmcnt 3-slot pipeline: proven race-free, 3.44
//   TB/s at 1 blk/CU) and r5 (fused x3 staging: minimal bytes, 666 µs best).
//   gemm_x3p: BM=BN=128, BK=32, 512 thr (8 waves, 32x64/wave), 3-slot LDS
//   rotation (3 x 32 KB = 96 KB), stage tile t+2 while computing t,
//   vmcnt(4) per step (never 0 mid-loop), raw s_barrier pair per step,
//   setprio around MFMA. BK=32 half-line overfetch (r7: +45%) should not
//   recur at 1 blk/CU: sibling 64B consumed 1 step later << L2 turnover.
//   gemm_f16p: same structure, 2 tiles/slot (48 KB -> 2 blk/CU).
//   K2/K4 get a 3D XCD swizzle confining 4 complete batches per XCD
//   (cuts enc L2-miss re-reads). K1/K5 keep the r5 xy-swizzle.
//   Preps / softmax / grids / fallback: identical to r5 (666 µs).
//
//   K1: z  = q·W_in^T        bf16x3 fused, out z_hi/z_lo bf16   [xy swizzle]
//   K2: P  = z·enc^T         bf16x3 fused, batched, fp32 -> d_out [bz swizzle]
//   K3: softmax (==0 -> -inf quirk), fp32 -> Pb fp16
//   K4: C  = Pb·eT^T         fp16, out C_f16                     [bz swizzle]
//   K5: out= tanh([C,q]·W_out^T + b)  fp16 2-chunk, fp32 -> d_out [xy swizzle]

// ---------------------------------------------------------------- helpers
__device__ inline unsigned short f2bf(float x) {           // RNE float->bf16
    unsigned int u = __float_as_uint(x);
    u += 0x7fffu + ((u >> 16) & 1u);
    return (unsigned short)(u >> 16);
}
__device__ inline float bf2f(unsigned short h) {
    return __uint_as_float(((unsigned int)h) << 16);
}
__device__ inline unsigned short f2h(float x) {            // RNE float->fp16
    _Float16 h = (_Float16)x;
    return *(unsigned short*)&h;
}

typedef __attribute__((ext_vector_type(8))) short    short8; // 8 bf16
typedef __attribute__((ext_vector_type(8))) _Float16 half8;  // 8 fp16
typedef __attribute__((ext_vector_type(4))) float    f32x4;

__device__ inline void gld_lds16(const void* g, void* l) {
    __builtin_amdgcn_global_load_lds(
        (const __attribute__((address_space(1))) unsigned int*)g,
        (__attribute__((address_space(3))) unsigned int*)l, 16, 0, 0);
}

#define BAR() do { asm volatile("" ::: "memory"); \
                   __builtin_amdgcn_s_barrier();  \
                   asm volatile("" ::: "memory"); } while (0)
#define LGKM0() do { asm volatile("s_waitcnt lgkmcnt(0)" ::: "memory"); \
                     __builtin_amdgcn_sched_barrier(0); } while (0)
#define VMW(n) asm volatile("s_waitcnt vmcnt(" #n ")" ::: "memory")

// BK=32 tile: [row][4 granules of 8 shorts]; granule g of row r stored at
// slot g ^ ((r>>1)&3) -> <=2-way bank aliasing (free, m136; r7 measured 0).
__device__ inline short8 frag_ld32(const short* Ls, int rowbase, int lane) {
    const int r = lane & 15, q = lane >> 4;
    return *(const short8*)&Ls[(rowbase + r) * 32 + ((q ^ ((r >> 1) & 3)) << 3)];
}
__device__ inline half8 frag_ld32_h(const short* Ls, int rowbase, int lane) {
    const int r = lane & 15, q = lane >> 4;
    return *(const half8*)&Ls[(rowbase + r) * 32 + ((q ^ ((r >> 1) & 3)) << 3)];
}

// stage 32 rows of a [128][32]-short tile (2 issues), linear LDS dest,
// global src pre-swizzled to match frag_ld32's layout.
__device__ inline void stage32(const unsigned short* g, long ld, short* lds,
                               int rw, int lane) {
    const int lr   = lane >> 2;
    const int glog = (lane & 3) ^ ((lr >> 1) & 3);
#pragma unroll
    for (int seg = 0; seg < 2; ++seg) {
        const int row = rw + seg * 16 + lr;
        gld_lds16(g + (long)row * ld + (glog << 3), lds + (rw + seg * 16) * 32);
    }
}
// stage 64 rows (4 issues)
__device__ inline void stage64(const unsigned short* g, long ld, short* lds,
                               int rw, int lane) {
    const int lr   = lane >> 2;
    const int glog = (lane & 3) ^ ((lr >> 1) & 3);
#pragma unroll
    for (int seg = 0; seg < 4; ++seg) {
        const int row = rw + seg * 16 + lr;
        gld_lds16(g + (long)row * ld + (glog << 3), lds + (rw + seg * 16) * 32);
    }
}

// SWZ_MODE 1: xy XCD swizzle (z==1 grids, (gx*gy)%8==0).
// SWZ_MODE 2: full-3D swizzle -> each XCD owns nwg/8 consecutive tile ids,
//             i.e. 4 complete batches for the (8,4,32) grids.
template<int MODE>
__device__ inline void swz3(int& bx, int& by, int& bz) {
    if constexpr (MODE == 1) {
        const int gx = gridDim.x;
        const int nwg = gx * gridDim.y;
        const int lin = by * gx + bx;
        const int cpx = nwg >> 3;
        const int s = (lin & 7) * cpx + (lin >> 3);
        bx = s % gx; by = s / gx;
    } else if constexpr (MODE == 2) {
        const int gx = gridDim.x, gy = gridDim.y;
        const int nwg = gx * gy * gridDim.z;
        const int lin = (bz * gy + by) * gx + bx;
        const int cpx = nwg >> 3;
        const int s = (lin & 7) * cpx + (lin >> 3);
        bx = s % gx; by = (s / gx) % gy; bz = s / (gx * gy);
    }
}

// ------------------------------------------------- pipelined fused bf16x3
// C = Ah·Bh^T + Ah·Bl^T + Al·Bh^T, 128x128 tile, BK=32, 512 thr.
// 3-slot rotation; per step: issue stage(t+2) -> ds_read(t) -> vmcnt(4)
// -> BAR -> MFMA(t) -> BAR.  OUT_MODE: 1 = hi/lo bf16 out, 2 = fp32 out.
template<int OUT_MODE, int SWZ>
__global__ __launch_bounds__(512, 2)
void gemm_x3p(const unsigned short* __restrict__ Ahg, const unsigned short* __restrict__ Alg,
              const unsigned short* __restrict__ Bhg, const unsigned short* __restrict__ Blg,
              float* __restrict__ Of, unsigned short* __restrict__ Oh,
              unsigned short* __restrict__ Ol,
              int NT, long lda, long ldb, long ldc, long sA, long sB, long sC)
{
    __shared__ short SL[3 * 4 * 4096];   // [slot][tile Ah,Al,Bh,Bl][128*32]

    const int tid  = threadIdx.x;
    const int wave = tid >> 6, lane = tid & 63;
    const int wm = (wave & 3) << 5;      // 0,32,64,96
    const int wn = (wave >> 2) << 6;     // 0,64
    int bxi = blockIdx.x, byi = blockIdx.y, bzi = blockIdx.z;
    swz3<SWZ>(bxi, byi, bzi);
    const long m0 = (long)byi * 128, n0 = (long)bxi * 128;

    // staging role: wave -> tile (0=Ah,1=Al,2=Bh,3=Bl), row half
    const int wtile = wave >> 1;
    const int wrow  = (wave & 1) << 6;
    const unsigned short* gA = (wtile == 0) ? Ahg : Alg;
    const unsigned short* gB = (wtile == 2) ? Bhg : Blg;
    const unsigned short* g0 = (wtile < 2)
        ? gA + (long)bzi * sA + m0 * lda
        : gB + (long)bzi * sB + n0 * ldb;
    const long gld = (wtile < 2) ? lda : ldb;

    f32x4 acc[2][4];
#pragma unroll
    for (int i = 0; i < 2; ++i)
#pragma unroll
        for (int j = 0; j < 4; ++j) acc[i][j] = (f32x4){0.f, 0.f, 0.f, 0.f};

    // prologue: stage slots 0 and 1
    stage64(g0,      gld, SL + 0 * 16384 + wtile * 4096, wrow, lane);
    stage64(g0 + 32, gld, SL + 1 * 16384 + wtile * 4096, wrow, lane);
    VMW(4);            // slot 0 landed (own 4); slot 1 in flight
    BAR();

    for (int t = 0; t < NT; ++t) {
        const int s = t % 3;
        const short* As = SL + s * 16384;

        const bool st = (t + 2) < NT;
        if (st) {
            const int s2 = (t + 2) % 3;
            stage64(g0 + (long)(t + 2) * 32, gld,
                    SL + s2 * 16384 + wtile * 4096, wrow, lane);
        }

        short8 ah[2], al[2], bh[4], bl[4];
#pragma unroll
        for (int i = 0; i < 2; ++i) ah[i] = frag_ld32(As + 0 * 4096, wm + i * 16, lane);
#pragma unroll
        for (int i = 0; i < 2; ++i) al[i] = frag_ld32(As + 1 * 4096, wm + i * 16, lane);
#pragma unroll
        for (int j = 0; j < 4; ++j) bh[j] = frag_ld32(As + 2 * 4096, wn + j * 16, lane);
#pragma unroll
        for (int j = 0; j < 4; ++j) bl[j] = frag_ld32(As + 3 * 4096, wn + j * 16, lane);

        if (st) { VMW(4); } else { VMW(0); }
        BAR();
        LGKM0();
        __builtin_amdgcn_s_setprio(1);
#pragma unroll
        for (int i = 0; i < 2; ++i)
#pragma unroll
            for (int j = 0; j < 4; ++j)
                acc[i][j] = __builtin_amdgcn_mfma_f32_16x16x32_bf16(ah[i], bh[j], acc[i][j], 0, 0, 0);
#pragma unroll
        for (int i = 0; i < 2; ++i)
#pragma unroll
            for (int j = 0; j < 4; ++j)
                acc[i][j] = __builtin_amdgcn_mfma_f32_16x16x32_bf16(ah[i], bl[j], acc[i][j], 0, 0, 0);
#pragma unroll
        for (int i = 0; i < 2; ++i)
#pragma unroll
            for (int j = 0; j < 4; ++j)
                acc[i][j] = __builtin_amdgcn_mfma_f32_16x16x32_bf16(al[i], bh[j], acc[i][j], 0, 0, 0);
        __builtin_amdgcn_s_setprio(0);
        BAR();
    }

    // epilogue — C/D map: col = lane&15, row = (lane>>4)*4 + reg (m89)
    const int q = lane >> 4, r = lane & 15;
#pragma unroll
    for (int i = 0; i < 2; ++i)
#pragma unroll
        for (int rr = 0; rr < 4; ++rr) {
            const long grow = m0 + wm + i * 16 + q * 4 + rr;
#pragma unroll
            for (int j = 0; j < 4; ++j) {
                const long gcol = n0 + wn + j * 16 + r;
                const float v = acc[i][j][rr];
                const long off = (long)bzi * sC + grow * ldc + gcol;
                if constexpr (OUT_MODE == 1) {
                    unsigned short h = f2bf(v);
                    Oh[off] = h;
                    Ol[off] = f2bf(v - bf2f(h));
                } else {
                    Of[off] = v;
                }
            }
        }
}

// ------------------------------------------------- pipelined fp16 GEMM
// Same discipline, 2 tiles/slot (48 KB -> 2 blk/CU). chunkK fixed at 1024
// (32 tiles of BK=32 per chunk). OUT_MODE: 0 = fp16 out, 3 = tanh+bias fp32.
template<int NCHUNK, int OUT_MODE, int SWZ>
__global__ __launch_bounds__(512, 2)
void gemm_f16p(const unsigned short* __restrict__ A0, const unsigned short* __restrict__ A1,
               const unsigned short* __restrict__ B0, const unsigned short* __restrict__ B1,
               float* __restrict__ Of, unsigned short* __restrict__ Oh,
               const float* __restrict__ bias,
               int NT, long lda, long ldb, long ldc, long sA, long sB, long sC)
{
    __shared__ short SL[3 * 2 * 4096];   // [slot][tile A,B][128*32]

    const int tid  = threadIdx.x;
    const int wave = tid >> 6, lane = tid & 63;
    const int wm = (wave & 3) << 5;
    const int wn = (wave >> 2) << 6;
    int bxi = blockIdx.x, byi = blockIdx.y, bzi = blockIdx.z;
    swz3<SWZ>(bxi, byi, bzi);
    const long m0 = (long)byi * 128, n0 = (long)bxi * 128;

    const int wtile = wave >> 2;         // 0=A, 1=B
    const int wrow  = (wave & 3) << 5;
    const long gld  = (wtile == 0) ? lda : ldb;
    const long gbase = (wtile == 0) ? ((long)bzi * sA + m0 * lda)
                                    : ((long)bzi * sB + n0 * ldb);
    const unsigned short* gc0 = ((wtile == 0) ? A0 : B0) + gbase;
    const unsigned short* gc1 = ((NCHUNK > 1) ? ((wtile == 0) ? A1 : B1) : nullptr);
    if (NCHUNK > 1 && gc1) gc1 += gbase;

    f32x4 acc[2][4];
#pragma unroll
    for (int i = 0; i < 2; ++i)
#pragma unroll
        for (int j = 0; j < 4; ++j) acc[i][j] = (f32x4){0.f, 0.f, 0.f, 0.f};

    // prologue (tiles 0,1 always in chunk 0)
    stage32(gc0,      gld, SL + 0 * 8192 + wtile * 4096, wrow, lane);
    stage32(gc0 + 32, gld, SL + 1 * 8192 + wtile * 4096, wrow, lane);
    VMW(2);
    BAR();

    for (int t = 0; t < NT; ++t) {
        const int s = t % 3;
        const short* As = SL + s * 8192;

        const bool st = (t + 2) < NT;
        if (st) {
            const int t2 = t + 2;
            const unsigned short* gc = (NCHUNK > 1 && t2 >= 32) ? gc1 : gc0;
            const long kk = (long)(t2 & 31) << 5;
            const int s2 = t2 % 3;
            stage32(gc + kk, gld, SL + s2 * 8192 + wtile * 4096, wrow, lane);
        }

        half8 af[2], bf[4];
#pragma unroll
        for (int i = 0; i < 2; ++i) af[i] = frag_ld32_h(As + 0 * 4096, wm + i * 16, lane);
#pragma unroll
        for (int j = 0; j < 4; ++j) bf[j] = frag_ld32_h(As + 1 * 4096, wn + j * 16, lane);

        if (st) { VMW(2); } else { VMW(0); }
        BAR();
        LGKM0();
        __builtin_amdgcn_s_setprio(1);
#pragma unroll
        for (int i = 0; i < 2; ++i)
#pragma unroll
            for (int j = 0; j < 4; ++j)
                acc[i][j] = __builtin_amdgcn_mfma_f32_16x16x32_f16(af[i], bf[j], acc[i][j], 0, 0, 0);
        __builtin_amdgcn_s_setprio(0);
        BAR();
    }

    const int q = lane >> 4, r = lane & 15;
#pragma unroll
    for (int i = 0; i < 2; ++i)
#pragma unroll
        for (int rr = 0; rr < 4; ++rr) {
            const long grow = m0 + wm + i * 16 + q * 4 + rr;
#pragma unroll
            for (int j = 0; j < 4; ++j) {
                const long gcol = n0 + wn + j * 16 + r;
                const float v = acc[i][j][rr];
                const long off = (long)bzi * sC + grow * ldc + gcol;
                if constexpr (OUT_MODE == 0) {
                    Oh[off] = f2h(v);
                } else {
                    Of[off] = tanhf(v + bias[gcol]);
                }
            }
        }
}

// ---------------------------------------------------------------- casts
template<bool Q16>
__global__ __launch_bounds__(256)
void split_q_k(const float* __restrict__ x, unsigned short* __restrict__ hi,
               unsigned short* __restrict__ lo, unsigned short* __restrict__ h16,
               int n4)
{
    const int i = blockIdx.x * 256 + threadIdx.x;
    if (i >= n4) return;
    const float4 v = ((const float4*)x)[i];
    ushort4 h, l;
    h.x = f2bf(v.x); h.y = f2bf(v.y); h.z = f2bf(v.z); h.w = f2bf(v.w);
    l.x = f2bf(v.x - bf2f(h.x)); l.y = f2bf(v.y - bf2f(h.y));
    l.z = f2bf(v.z - bf2f(h.z)); l.w = f2bf(v.w - bf2f(h.w));
    ((ushort4*)hi)[i] = h;
    ((ushort4*)lo)[i] = l;
    if constexpr (Q16) {
        ushort4 f;
        f.x = f2h(v.x); f.y = f2h(v.y); f.z = f2h(v.z); f.w = f2h(v.w);
        ((ushort4*)h16)[i] = f;
    }
}

__global__ __launch_bounds__(256)
void split_f32_bf16(const float* __restrict__ x, unsigned short* __restrict__ hi,
                    unsigned short* __restrict__ lo, int n4)
{
    const int i = blockIdx.x * 256 + threadIdx.x;
    if (i >= n4) return;
    const float4 v = ((const float4*)x)[i];
    ushort4 h, l;
    h.x = f2bf(v.x); h.y = f2bf(v.y); h.z = f2bf(v.z); h.w = f2bf(v.w);
    l.x = f2bf(v.x - bf2f(h.x)); l.y = f2bf(v.y - bf2f(h.y));
    l.z = f2bf(v.z - bf2f(h.z)); l.w = f2bf(v.w - bf2f(h.w));
    ((ushort4*)hi)[i] = h;
    ((ushort4*)lo)[i] = l;
}

__global__ __launch_bounds__(256)
void conv_f32_f16(const float* __restrict__ x, unsigned short* __restrict__ o, int n4)
{
    const int i = blockIdx.x * 256 + threadIdx.x;
    if (i >= n4) return;
    const float4 v = ((const float4*)x)[i];
    ushort4 h;
    h.x = f2h(v.x); h.y = f2h(v.y); h.z = f2h(v.z); h.w = f2h(v.w);
    ((ushort4*)o)[i] = h;
}

__global__ __launch_bounds__(256)
void prep_w_k(const float* __restrict__ Wi, unsigned short* __restrict__ Wih,
              unsigned short* __restrict__ Wil,
              const float* __restrict__ Wo, unsigned short* __restrict__ Wo16)
{
    const int i = blockIdx.x * 256 + threadIdx.x;
    if (i < 262144) {
        const float4 v = ((const float4*)Wi)[i];
        ushort4 h, l;
        h.x = f2bf(v.x); h.y = f2bf(v.y); h.z = f2bf(v.z); h.w = f2bf(v.w);
        l.x = f2bf(v.x - bf2f(h.x)); l.y = f2bf(v.y - bf2f(h.y));
        l.z = f2bf(v.z - bf2f(h.z)); l.w = f2bf(v.w - bf2f(h.w));
        ((ushort4*)Wih)[i] = h;
        ((ushort4*)Wil)[i] = l;
    } else {
        const int j = i - 262144;
        if (j < 524288) {
            const float4 v = ((const float4*)Wo)[j];
            ushort4 h;
            h.x = f2h(v.x); h.y = f2h(v.y); h.z = f2h(v.z); h.w = f2h(v.w);
            ((ushort4*)Wo16)[j] = h;
        }
    }
}

// enc fp32 [S,B,H] -> e_hi/e_lo bf16 [S,B,H] AND eT fp16 [B][H][S], one read.
__global__ __launch_bounds__(256)
void split_enc_t(const float* __restrict__ E, unsigned short* __restrict__ Eh,
                 unsigned short* __restrict__ El, unsigned short* __restrict__ ET)
{
    __shared__ unsigned short L[64][72];
    const int s0 = blockIdx.x * 64, h0 = blockIdx.y * 64, b = blockIdx.z;
    const int tid = threadIdx.x;
#pragma unroll
    for (int io = 0; io < 2; ++io) {
        const int g = io * 256 + tid;
        const int rs = g >> 3, c8 = (g & 7) * 8;
        const long base = ((long)(s0 + rs) * 32 + b) * 1024 + h0 + c8;
        const float4 v0 = *(const float4*)(E + base);
        const float4 v1 = *(const float4*)(E + base + 4);
        const float vv[8] = {v0.x, v0.y, v0.z, v0.w, v1.x, v1.y, v1.z, v1.w};
        unsigned short hi[8], lo[8];
#pragma unroll
        for (int j = 0; j < 8; ++j) {
            hi[j] = f2bf(vv[j]);
            lo[j] = f2bf(vv[j] - bf2f(hi[j]));
            L[rs][c8 + j] = f2h(vv[j]);
        }
        *(ushort4*)(Eh + base)     = *(const ushort4*)&hi[0];
        *(ushort4*)(Eh + base + 4) = *(const ushort4*)&hi[4];
        *(ushort4*)(El + base)     = *(const ushort4*)&lo[0];
        *(ushort4*)(El + base + 4) = *(const ushort4*)&lo[4];
    }
    __syncthreads();
#pragma unroll
    for (int io = 0; io < 2; ++io) {
        const int g = io * 256 + tid;
        const int rh = g >> 3, c8 = (g & 7) * 8;
        unsigned short t[8];
#pragma unroll
        for (int j = 0; j < 8; ++j) t[j] = L[c8 + j][rh];
        unsigned short* dst = ET + ((long)b * 1024 + h0 + rh) * 1024 + s0 + c8;
        *(ushort4*)(dst)     = *(const ushort4*)&t[0];
        *(ushort4*)(dst + 4) = *(const ushort4*)&t[4];
    }
}

// enc fp32 [S,B,H] -> eT fp16 [B][H][S]; 64x64 tiles (small-ws path)
__global__ __launch_bounds__(256)
void transpose_enc_f16(const float* __restrict__ E, unsigned short* __restrict__ ET)
{
    __shared__ unsigned short L[64][72];
    const int s0 = blockIdx.x * 64, h0 = blockIdx.y * 64, b = blockIdx.z;
    const int tid = threadIdx.x;
#pragma unroll
    for (int io = 0; io < 2; ++io) {
        const int g = io * 256 + tid;
        const int rs = g >> 3, c8 = (g & 7) * 8;
        const float* src = E + ((long)(s0 + rs) * 32 + b) * 1024 + h0 + c8;
        const float4 v0 = *(const float4*)(src);
        const float4 v1 = *(const float4*)(src + 4);
        L[rs][c8 + 0] = f2h(v0.x); L[rs][c8 + 1] = f2h(v0.y);
        L[rs][c8 + 2] = f2h(v0.z); L[rs][c8 + 3] = f2h(v0.w);
        L[rs][c8 + 4] = f2h(v1.x); L[rs][c8 + 5] = f2h(v1.y);
        L[rs][c8 + 6] = f2h(v1.z); L[rs][c8 + 7] = f2h(v1.w);
    }
    __syncthreads();
#pragma unroll
    for (int io = 0; io < 2; ++io) {
        const int g = io * 256 + tid;
        const int rh = g >> 3, c8 = (g & 7) * 8;
        unsigned short t[8];
#pragma unroll
        for (int j = 0; j < 8; ++j) t[j] = L[c8 + j][rh];
        unsigned short* dst = ET + ((long)b * 1024 + h0 + rh) * 1024 + s0 + c8;
        *(ushort4*)(dst)     = *(const ushort4*)&t[0];
        *(ushort4*)(dst + 4) = *(const ushort4*)&t[4];
    }
}

// -------------------------------------------------- softmax (fp16 out)
__global__ __launch_bounds__(256)
void softmax_p_f16(const float* __restrict__ P, unsigned short* __restrict__ Pb)
{
    const int row  = blockIdx.x * 4 + (threadIdx.x >> 6);
    const int lane = threadIdx.x & 63;
    const float* p = P + (long)row * 1024 + lane * 4;
    unsigned short* pb = Pb + (long)row * 1024 + lane * 4;

    float4 v[4];
    float mx = -INFINITY;
#pragma unroll
    for (int i = 0; i < 4; ++i) {
        v[i] = *(const float4*)(p + i * 256);
        v[i].x = (v[i].x == 0.f) ? -INFINITY : v[i].x;
        v[i].y = (v[i].y == 0.f) ? -INFINITY : v[i].y;
        v[i].z = (v[i].z == 0.f) ? -INFINITY : v[i].z;
        v[i].w = (v[i].w == 0.f) ? -INFINITY : v[i].w;
        mx = fmaxf(mx, fmaxf(fmaxf(v[i].x, v[i].y), fmaxf(v[i].z, v[i].w)));
    }
#pragma unroll
    for (int o = 32; o > 0; o >>= 1) mx = fmaxf(mx, __shfl_xor(mx, o, 64));

    float sum = 0.f;
#pragma unroll
    for (int i = 0; i < 4; ++i) {
        v[i].x = __expf(v[i].x - mx); v[i].y = __expf(v[i].y - mx);
        v[i].z = __expf(v[i].z - mx); v[i].w = __expf(v[i].w - mx);
        sum += v[i].x + v[i].y + v[i].z + v[i].w;
    }
#pragma unroll
    for (int o = 32; o > 0; o >>= 1) sum += __shfl_xor(sum, o, 64);

    const float inv = 1.f / sum;
#pragma unroll
    for (int i = 0; i < 4; ++i) {
        ushort4 u;
        u.x = f2h(v[i].x * inv); u.y = f2h(v[i].y * inv);
        u.z = f2h(v[i].z * inv); u.w = f2h(v[i].w * inv);
        *(ushort4*)(pb + i * 256) = u;
    }
}

// ================================================================ fallback
// (verified round-1 fp32 path, used only if ws_size < 264 MiB)
#define BM 128
#define BN 128
#define BKT 16

template<bool BT, bool DO_TANH, bool CAT_A>
__global__ __launch_bounds__(256)
void sgemm(const float* __restrict__ A, const float* __restrict__ A2,
           const float* __restrict__ Bmat, const float* __restrict__ bias,
           float* __restrict__ C,
           int M, int N, int K, int Ksplit,
           int lda, int ldb, int ldc,
           long sA, long sB, long sC)
{
    __shared__ float Asb[BKT][BM];
    __shared__ float Bsb[BKT][BN];

    const int bz = blockIdx.z;
    const float* Ab = A + (long)bz * sA;
    const float* Bb = Bmat + (long)bz * sB;
    float* Cb = C + (long)bz * sC;

    const int tid = threadIdx.x;
    const int m0 = blockIdx.y * BM;
    const int n0 = blockIdx.x * BN;
    const int tx = tid & 15;
    const int ty = tid >> 4;

    float acc[8][8];
#pragma unroll
    for (int i = 0; i < 8; ++i)
#pragma unroll
        for (int j = 0; j < 8; ++j) acc[i][j] = 0.f;

    for (int kk = 0; kk < K; kk += BKT) {
        const float* Asrc = Ab;
        int acol = kk;
        if constexpr (CAT_A) {
            if (kk >= Ksplit) { Asrc = A2; acol = kk - Ksplit; }
        }
#pragma unroll
        for (int i = 0; i < 2; ++i) {
            int f = i * 256 + tid;
            int row = f >> 2;
            int k4 = (f & 3) << 2;
            float4 v = *(const float4*)(Asrc + (long)(m0 + row) * lda + acol + k4);
            Asb[k4 + 0][row] = v.x; Asb[k4 + 1][row] = v.y;
            Asb[k4 + 2][row] = v.z; Asb[k4 + 3][row] = v.w;
        }
        if constexpr (BT) {
#pragma unroll
            for (int i = 0; i < 2; ++i) {
                int f = i * 256 + tid;
                int row = f >> 2;
                int k4 = (f & 3) << 2;
                float4 v = *(const float4*)(Bb + (long)(n0 + row) * ldb + kk + k4);
                Bsb[k4 + 0][row] = v.x; Bsb[k4 + 1][row] = v.y;
                Bsb[k4 + 2][row] = v.z; Bsb[k4 + 3][row] = v.w;
            }
        } else {
#pragma unroll
            for (int i = 0; i < 2; ++i) {
                int f = i * 256 + tid;
                int kr = f >> 5;
                int n4 = (f & 31) << 2;
                float4 v = *(const float4*)(Bb + (long)(kk + kr) * ldb + n0 + n4);
                *(float4*)&Bsb[kr][n4] = v;
            }
        }
        __syncthreads();
#pragma unroll
        for (int k = 0; k < BKT; ++k) {
            float a[8], bv[8];
            *(float4*)&a[0]  = *(const float4*)&Asb[k][ty * 4];
            *(float4*)&a[4]  = *(const float4*)&Asb[k][ty * 4 + 64];
            *(float4*)&bv[0] = *(const float4*)&Bsb[k][tx * 4];
            *(float4*)&bv[4] = *(const float4*)&Bsb[k][tx * 4 + 64];
#pragma unroll
            for (int i = 0; i < 8; ++i)
#pragma unroll
                for (int j = 0; j < 8; ++j)
                    acc[i][j] = fmaf(a[i], bv[j], acc[i][j]);
        }
        __syncthreads();
    }
#pragma unroll
    for (int i = 0; i < 8; ++i) {
        int rrow = m0 + ty * 4 + (i & 3) + ((i >> 2) << 6);
        float* crow = Cb + (long)rrow * ldc;
#pragma unroll
        for (int jj = 0; jj < 2; ++jj) {
            int c0 = n0 + tx * 4 + jj * 64;
            float4 v;
            v.x = acc[i][jj * 4 + 0]; v.y = acc[i][jj * 4 + 1];
            v.z = acc[i][jj * 4 + 2]; v.w = acc[i][jj * 4 + 3];
            if constexpr (DO_TANH) {
                v.x = tanhf(v.x + bias[c0 + 0]); v.y = tanhf(v.y + bias[c0 + 1]);
                v.z = tanhf(v.z + bias[c0 + 2]); v.w = tanhf(v.w + bias[c0 + 3]);
            }
            *(float4*)(crow + c0) = v;
        }
    }
}

__global__ __launch_bounds__(256)
void softmax_rows(float* __restrict__ P)
{
    const int row = blockIdx.x * 4 + (threadIdx.x >> 6);
    const int lane = threadIdx.x & 63;
    float* p = P + (long)row * 1024 + lane * 4;
    float4 v[4];
    float mx = -INFINITY;
#pragma unroll
    for (int i = 0; i < 4; ++i) {
        v[i] = *(const float4*)(p + i * 256);
        v[i].x = (v[i].x == 0.f) ? -INFINITY : v[i].x;
        v[i].y = (v[i].y == 0.f) ? -INFINITY : v[i].y;
        v[i].z = (v[i].z == 0.f) ? -INFINITY : v[i].z;
        v[i].w = (v[i].w == 0.f) ? -INFINITY : v[i].w;
        mx = fmaxf(mx, fmaxf(fmaxf(v[i].x, v[i].y), fmaxf(v[i].z, v[i].w)));
    }
#pragma unroll
    for (int o = 32; o > 0; o >>= 1) mx = fmaxf(mx, __shfl_xor(mx, o, 64));
    float sum = 0.f;
#pragma unroll
    for (int i = 0; i < 4; ++i) {
        v[i].x = __expf(v[i].x - mx); v[i].y = __expf(v[i].y - mx);
        v[i].z = __expf(v[i].z - mx); v[i].w = __expf(v[i].w - mx);
        sum += v[i].x + v[i].y + v[i].z + v[i].w;
    }
#pragma unroll
    for (int o = 32; o > 0; o >>= 1) sum += __shfl_xor(sum, o, 64);
    const float inv = 1.f / sum;
#pragma unroll
    for (int i = 0; i < 4; ++i) {
        v[i].x *= inv; v[i].y *= inv; v[i].z *= inv; v[i].w *= inv;
        *(float4*)(p + i * 256) = v[i];
    }
}

// ================================================================ launch
extern "C" void kernel_launch(void* const* d_in, const int* in_sizes, int n_in,
                              void* d_out, int out_size, void* d_ws, size_t ws_size,
                              hipStream_t stream)
{
    (void)in_sizes; (void)n_in; (void)out_size;
    const int Bv = 32, T = 512, S = 1024, H = 1024;

    const float* q     = (const float*)d_in[0];
    const float* enc   = (const float*)d_in[1];
    const float* W_in  = (const float*)d_in[3];
    const float* W_out = (const float*)d_in[4];
    const float* b_out = (const float*)d_in[5];
    float* out = (float*)d_out;

    const size_t need = 264ull << 20;
    if (ws_size >= need) {
        const bool big = ws_size >= (360ull << 20);

        char* w = (char*)d_ws;
        unsigned short* q_hi  = (unsigned short*)(w);                  // K1
        unsigned short* q_lo  = (unsigned short*)(w + (32ull << 20));  // K1; then Pb fp16
        unsigned short* z_hi  = (unsigned short*)(w + (64ull << 20));  // K1->K2; then C_f16
        unsigned short* z_lo  = (unsigned short*)(w + (96ull << 20));  // K1->K2; then q_f16 (small ws)
        unsigned short* e_hi  = (unsigned short*)(w + (128ull << 20)); // K2
        unsigned short* e_lo  = (unsigned short*)(w + (192ull << 20)); // K2; then eT fp16 (small ws)
        unsigned short* Wi_hi = (unsigned short*)(w + (256ull << 20));
        unsigned short* Wi_lo = (unsigned short*)(w + (258ull << 20));
        unsigned short* Wo16  = (unsigned short*)(w + (260ull << 20));
        // big-ws extras (past 264 MiB):
        unsigned short* q16b  = (unsigned short*)(w + (264ull << 20)); // 32 MiB
        unsigned short* eTb   = (unsigned short*)(w + (296ull << 20)); // 64 MiB

        unsigned short* Pb  = q_lo;                 // fp16, after softmax
        unsigned short* q16 = big ? q16b : z_lo;    // fp16
        unsigned short* eT  = big ? eTb  : e_lo;    // fp16
        unsigned short* C16 = z_hi;                 // fp16, after K2

        // ---- prep passes. enc first, q-split LAST before K1 (L3 residency).
        if (big) split_enc_t<<<dim3(16, 16, 32), 256, 0, stream>>>(enc, e_hi, e_lo, eTb);
        else     split_f32_bf16<<<32768, 256, 0, stream>>>(enc, e_hi, e_lo, 8388608);
        prep_w_k<<<3072, 256, 0, stream>>>(W_in, Wi_hi, Wi_lo, W_out, Wo16);
        if (big) split_q_k<true ><<<16384, 256, 0, stream>>>(q, q_hi, q_lo, q16b, 4194304);
        else     split_q_k<false><<<16384, 256, 0, stream>>>(q, q_hi, q_lo, nullptr, 4194304);

        // K1: z = q·W_in^T  (pipelined fused bf16x3), out z_hi/z_lo [xy swz]
        gemm_x3p<1, 1><<<dim3(8, 128, 1), 512, 0, stream>>>(
            q_hi, q_lo, Wi_hi, Wi_lo,
            nullptr, z_hi, z_lo,
            32, 1024, 1024, 1024, 0, 0, 0);

        // K2: P_b = z_b·enc_b^T (pipelined fused bf16x3), fp32 -> d_out
        //     [3D swizzle: 4 complete batches per XCD]
        gemm_x3p<2, 2><<<dim3(8, 4, 32), 512, 0, stream>>>(
            z_hi, z_lo, e_hi, e_lo,
            (float*)d_out, nullptr, nullptr,
            32, 1024, (long)Bv * H, 1024,
            (long)T * H, (long)H, (long)T * S);

        // K3: masked softmax, fp32 -> fp16 Pb
        softmax_p_f16<<<(Bv * T) / 4, 256, 0, stream>>>((const float*)d_out, Pb);

        // small-ws: materialize q16/eT now (slots freed by K2)
        if (!big) {
            conv_f32_f16<<<16384, 256, 0, stream>>>(q, q16, 4194304);
            transpose_enc_f16<<<dim3(16, 16, 32), 256, 0, stream>>>(enc, eT);
        }

        // K4: C_b = Pb_b · eT_b^T  (pipelined fp16), out C_f16  [3D swizzle]
        gemm_f16p<1, 0, 2><<<dim3(8, 4, 32), 512, 0, stream>>>(
            Pb, nullptr, eT, nullptr,
            nullptr, C16, nullptr,
            32, 1024, 1024, 1024,
            (long)T * S, (long)H * S, (long)T * H);

        // K5: out = tanh([C,q]·W_out^T + b) (pipelined fp16, 2 chunks) [xy swz]
        gemm_f16p<2, 3, 1><<<dim3(8, 128, 1), 512, 0, stream>>>(
            C16, q16, Wo16, Wo16 + 1024,
            (float*)d_out, nullptr, b_out,
            64, 1024, 2048, 1024, 0, 0, 0);
    } else {
        // -------- fallback: round-1 fp32 path --------
        float* Z = (float*)d_ws;
        float* P = Z + (size_t)Bv * T * H;
        dim3 blk(256);
        sgemm<true, false, false><<<dim3(H / BN, (Bv * T) / BM, 1), blk, 0, stream>>>(
            q, nullptr, W_in, nullptr, Z,
            Bv * T, H, H, 0, H, H, H, 0, 0, 0);
        sgemm<true, false, false><<<dim3(S / BN, T / BM, Bv), blk, 0, stream>>>(
            Z, nullptr, enc, nullptr, P,
            T, S, H, 0, H, Bv * H, S, (long)T * H, H, (long)T * S);
        softmax_rows<<<(Bv * T) / 4, blk, 0, stream>>>(P);
        sgemm<false, false, false><<<dim3(H / BN, T / BM, Bv), blk, 0, stream>>>(
            P, nullptr, enc, nullptr, Z,
            T, H, S, 0, S, Bv * H, H, (long)T * S, H, (long)T * H);
        sgemm<true, true, true><<<dim3(H / BN, (Bv * T) / BM, 1), blk, 0, stream>>>(
            Z, q, W_out, b_out, out,
            Bv * T, H, 2 * H, H, H, 2 * H, H, 0, 0, 0);
    }
}